// Round 7
// baseline (145.328 us; speedup 1.0000x reference)
//
#include <hip/hip_runtime.h>
#include <math.h>

#define N       8192
#define BLK     256
#define JCHUNK  256                  // B-points per block (one slice)
#define NSLICE  (N / JCHUNK)         // 32
#define ITILES  (N / BLK)            // 32
#define HALF    (ITILES * NSLICE)    // 1024 blocks per direction
#define GRID    (2 * HALF)           // 2048 = 8 blocks/CU, 32 waves/CU

// ---------------------------------------------------- precompute + init ----
// P[0..N) = target packed {x,y,z,|p|^2}; P[N..2N) = output packed.
// dmin[0..2N) = +inf bits; cnt = 0.
__global__ __launch_bounds__(BLK) void chamfer_prep_kernel(
        const float* __restrict__ tgt, const float* __restrict__ outp,
        float4* __restrict__ P, unsigned* __restrict__ dmin,
        unsigned* __restrict__ cnt) {
    int i = blockIdx.x * BLK + (int)threadIdx.x;   // 0 .. 2N-1
    if (i == 0) cnt[0] = 0u;
    const float* src = (i < N) ? tgt : outp;
    int k = (i < N) ? i : (i - N);
    float x = src[3 * k + 0];
    float y = src[3 * k + 1];
    float z = src[3 * k + 2];
    P[i] = make_float4(x, y, z, fmaf(x, x, fmaf(y, y, z * z)));
    dmin[i] = 0x7F800000u;  // +inf
}

// ---------------------------------------------------------------- dist ----
// Exact R2 structure (best measured: 31.7 us total) + two bounded changes:
//  (1) fused last-block sqrt-mean reduction (verified R4-R6),
//  (2) dual independent load streams (bp[j] and bp[j+128]) for 2x MLP.
// d^2 = |a|^2 + (|b|^2 - 2 a.b); |a|^2 commutes with min. 4 VALU ops/pair.
__global__ __launch_bounds__(BLK) void chamfer_dist_kernel(
        const float4* __restrict__ P, unsigned* __restrict__ dmin,
        unsigned* __restrict__ cnt,
        const int* __restrict__ curp, const int* __restrict__ subp,
        float* __restrict__ out) {
    __shared__ int   lastf;
    __shared__ float red1[BLK / 64], red2[BLK / 64];

    int tid = (int)threadIdx.x;
    int bid = (int)blockIdx.x;
    int dir = (bid >= HALF) ? 1 : 0;
    if (dir) bid -= HALF;
    int aoff = dir ? N : 0;
    int boff = dir ? 0 : N;

    int itile = bid / NSLICE;
    int slice = bid % NSLICE;
    int i = itile * BLK + tid;

    float4 a = P[aoff + i];
    float axm = -2.0f * a.x;
    float aym = -2.0f * a.y;
    float azm = -2.0f * a.z;

    const float inf = __builtin_inff();
    float m0 = inf, m1 = inf, m2 = inf, m3 = inf;
    float m4 = inf, m5 = inf, m6 = inf, m7 = inf;

    const float4* __restrict__ bp = P + boff + slice * JCHUNK;  // wave-uniform
    #pragma unroll 4
    for (int j = 0; j < JCHUNK / 2; j += 4) {
        float4 b0 = bp[j + 0];
        float4 b1 = bp[j + 1];
        float4 b2 = bp[j + 2];
        float4 b3 = bp[j + 3];
        float4 c0 = bp[j + 128];
        float4 c1 = bp[j + 129];
        float4 c2 = bp[j + 130];
        float4 c3 = bp[j + 131];
        m0 = fminf(m0, fmaf(axm, b0.x, fmaf(aym, b0.y, fmaf(azm, b0.z, b0.w))));
        m1 = fminf(m1, fmaf(axm, b1.x, fmaf(aym, b1.y, fmaf(azm, b1.z, b1.w))));
        m2 = fminf(m2, fmaf(axm, b2.x, fmaf(aym, b2.y, fmaf(azm, b2.z, b2.w))));
        m3 = fminf(m3, fmaf(axm, b3.x, fmaf(aym, b3.y, fmaf(azm, b3.z, b3.w))));
        m4 = fminf(m4, fmaf(axm, c0.x, fmaf(aym, c0.y, fmaf(azm, c0.z, c0.w))));
        m5 = fminf(m5, fmaf(axm, c1.x, fmaf(aym, c1.y, fmaf(azm, c1.z, c1.w))));
        m6 = fminf(m6, fmaf(axm, c2.x, fmaf(aym, c2.y, fmaf(azm, c2.z, c2.w))));
        m7 = fminf(m7, fmaf(axm, c3.x, fmaf(aym, c3.y, fmaf(azm, c3.z, c3.w))));
    }
    float m = fminf(fminf(fminf(m0, m1), fminf(m2, m3)),
                    fminf(fminf(m4, m5), fminf(m6, m7)));
    float d2 = fmaxf(a.w + m, 0.0f);
    atomicMin(&dmin[aoff + i], __float_as_uint(d2));   // coalesced, 1/thread

    // ---- last block to finish: fused sqrt-mean reduction ----
    __threadfence();
    if (tid == 0) lastf = (atomicAdd(cnt, 1u) == (unsigned)(gridDim.x - 1));
    __syncthreads();
    if (!lastf) return;
    __threadfence();   // acquire side

    int wid = tid >> 6, lane = tid & 63;
    float s1 = 0.0f, s2 = 0.0f;
    for (int t = tid; t < N; t += BLK) {
        unsigned u1 = __hip_atomic_load(&dmin[t],     __ATOMIC_RELAXED, __HIP_MEMORY_SCOPE_AGENT);
        unsigned u2 = __hip_atomic_load(&dmin[N + t], __ATOMIC_RELAXED, __HIP_MEMORY_SCOPE_AGENT);
        s1 += sqrtf(__uint_as_float(u1));
        s2 += sqrtf(__uint_as_float(u2));
    }
    #pragma unroll
    for (int off = 32; off > 0; off >>= 1) {
        s1 += __shfl_down(s1, off, 64);
        s2 += __shfl_down(s2, off, 64);
    }
    if (lane == 0) { red1[wid] = s1; red2[wid] = s2; }
    __syncthreads();
    if (tid == 0) {
        float t1 = 0.0f, t2 = 0.0f;
        #pragma unroll
        for (int w = 0; w < BLK / 64; ++w) { t1 += red1[w]; t2 += red2[w]; }
        int e = curp[0] / subp[0];
        double scale = 10.0 / pow(0.99, (double)e);
        out[0] = (float)((((double)t1 + (double)t2) / (double)N) * 0.5 * scale);
    }
}

// ---------------------------------------------------------------- launch ----
extern "C" void kernel_launch(void* const* d_in, const int* in_sizes, int n_in,
                              void* d_out, int out_size, void* d_ws, size_t ws_size,
                              hipStream_t stream) {
    const float* target = (const float*)d_in[0];   // (1, 8192, 3) f32
    const float* output = (const float*)d_in[1];   // (1, 8192, 3) f32
    const int*   curp   = (const int*)d_in[2];
    const int*   subp   = (const int*)d_in[3];
    float* out = (float*)d_out;

    // ws: float4 P[2N] (256 KB) | uint dmin[2N] (64 KB) | uint cnt
    float4*   P    = (float4*)d_ws;
    unsigned* dmin = (unsigned*)(P + 2 * N);
    unsigned* cnt  = dmin + 2 * N;

    chamfer_prep_kernel<<<2 * N / BLK, BLK, 0, stream>>>(target, output, P, dmin, cnt);
    chamfer_dist_kernel<<<GRID, BLK, 0, stream>>>(P, dmin, cnt, curp, subp, out);
}

// Round 8
// 31.455 us; speedup vs baseline: 4.6202x; 4.6202x over previous
//
#include <hip/hip_runtime.h>
#include <math.h>

#define N       8192
#define BLK     256
#define JCHUNK  256                  // B-points per block (one slice)
#define NSLICE  (N / JCHUNK)         // 32
#define ITILES  (N / BLK)            // 32
#define HALF    (ITILES * NSLICE)    // 1024 blocks per direction
#define GRID    (2 * HALF)           // 2048 = 8 blocks/CU, 32 waves/CU
#define RBLK    1024

// ---------------------------------------------------- precompute + init ----
// P[0..N) = target packed {x,y,z,|p|^2}; P[N..2N) = output packed.
// dmin[0..2N) = +inf bits.
__global__ __launch_bounds__(BLK) void chamfer_prep_kernel(
        const float* __restrict__ tgt, const float* __restrict__ outp,
        float4* __restrict__ P, unsigned* __restrict__ dmin) {
    int i = blockIdx.x * BLK + (int)threadIdx.x;   // 0 .. 2N-1
    const float* src = (i < N) ? tgt : outp;
    int k = (i < N) ? i : (i - N);
    float x = src[3 * k + 0];
    float y = src[3 * k + 1];
    float z = src[3 * k + 2];
    P[i] = make_float4(x, y, z, fmaf(x, x, fmaf(y, y, z * z)));
    dmin[i] = 0x7F800000u;  // +inf
}

// ---------------------------------------------------------------- dist ----
// Exact R2 structure (best measured: 31.7 us total). ONE change: 8 min
// accumulators over two independent scalar-load streams (bp[j], bp[j+128])
// for 2x memory-level parallelism. NO fence, NO completion counter --
// the kernel boundary provides cross-XCD ordering once, not per-block.
// d^2 = |a|^2 + (|b|^2 - 2 a.b); |a|^2 commutes with min. 4 VALU ops/pair.
__global__ __launch_bounds__(BLK) void chamfer_dist_kernel(
        const float4* __restrict__ P, unsigned* __restrict__ dmin) {
    int tid = (int)threadIdx.x;
    int bid = (int)blockIdx.x;
    int dir = (bid >= HALF) ? 1 : 0;
    if (dir) bid -= HALF;
    int aoff = dir ? N : 0;
    int boff = dir ? 0 : N;

    int itile = bid / NSLICE;
    int slice = bid % NSLICE;
    int i = itile * BLK + tid;

    float4 a = P[aoff + i];
    float axm = -2.0f * a.x;
    float aym = -2.0f * a.y;
    float azm = -2.0f * a.z;

    const float inf = __builtin_inff();
    float m0 = inf, m1 = inf, m2 = inf, m3 = inf;
    float m4 = inf, m5 = inf, m6 = inf, m7 = inf;

    const float4* __restrict__ bp = P + boff + slice * JCHUNK;  // wave-uniform
    #pragma unroll 4
    for (int j = 0; j < JCHUNK / 2; j += 4) {
        float4 b0 = bp[j + 0];
        float4 b1 = bp[j + 1];
        float4 b2 = bp[j + 2];
        float4 b3 = bp[j + 3];
        float4 c0 = bp[j + 128];
        float4 c1 = bp[j + 129];
        float4 c2 = bp[j + 130];
        float4 c3 = bp[j + 131];
        m0 = fminf(m0, fmaf(axm, b0.x, fmaf(aym, b0.y, fmaf(azm, b0.z, b0.w))));
        m1 = fminf(m1, fmaf(axm, b1.x, fmaf(aym, b1.y, fmaf(azm, b1.z, b1.w))));
        m2 = fminf(m2, fmaf(axm, b2.x, fmaf(aym, b2.y, fmaf(azm, b2.z, b2.w))));
        m3 = fminf(m3, fmaf(axm, b3.x, fmaf(aym, b3.y, fmaf(azm, b3.z, b3.w))));
        m4 = fminf(m4, fmaf(axm, c0.x, fmaf(aym, c0.y, fmaf(azm, c0.z, c0.w))));
        m5 = fminf(m5, fmaf(axm, c1.x, fmaf(aym, c1.y, fmaf(azm, c1.z, c1.w))));
        m6 = fminf(m6, fmaf(axm, c2.x, fmaf(aym, c2.y, fmaf(azm, c2.z, c2.w))));
        m7 = fminf(m7, fmaf(axm, c3.x, fmaf(aym, c3.y, fmaf(azm, c3.z, c3.w))));
    }
    float m = fminf(fminf(fminf(m0, m1), fminf(m2, m3)),
                    fminf(fminf(m4, m5), fminf(m6, m7)));
    float d2 = fmaxf(a.w + m, 0.0f);
    atomicMin(&dmin[aoff + i], __float_as_uint(d2));   // coalesced, 1/thread
}

// -------------------------------------------------------------- reduce ----
__global__ __launch_bounds__(RBLK) void chamfer_reduce_kernel(
        const unsigned* __restrict__ dmin,
        const int* __restrict__ curp, const int* __restrict__ subp,
        float* __restrict__ out) {
    __shared__ float sh1[RBLK / 64], sh2[RBLK / 64];
    int t = (int)threadIdx.x;
    float s1 = 0.0f, s2 = 0.0f;
    for (int i = t; i < N; i += RBLK) {
        s1 += sqrtf(__uint_as_float(dmin[i]));
        s2 += sqrtf(__uint_as_float(dmin[N + i]));
    }
    #pragma unroll
    for (int off = 32; off > 0; off >>= 1) {
        s1 += __shfl_down(s1, off, 64);
        s2 += __shfl_down(s2, off, 64);
    }
    int wid = t >> 6, lane = t & 63;
    if (lane == 0) { sh1[wid] = s1; sh2[wid] = s2; }
    __syncthreads();
    if (t == 0) {
        float t1 = 0.0f, t2 = 0.0f;
        #pragma unroll
        for (int w = 0; w < RBLK / 64; ++w) { t1 += sh1[w]; t2 += sh2[w]; }
        int e = curp[0] / subp[0];
        double scale = 10.0 / pow(0.99, (double)e);
        out[0] = (float)((((double)t1 + (double)t2) / (double)N) * 0.5 * scale);
    }
}

// ---------------------------------------------------------------- launch ----
extern "C" void kernel_launch(void* const* d_in, const int* in_sizes, int n_in,
                              void* d_out, int out_size, void* d_ws, size_t ws_size,
                              hipStream_t stream) {
    const float* target = (const float*)d_in[0];   // (1, 8192, 3) f32
    const float* output = (const float*)d_in[1];   // (1, 8192, 3) f32
    const int*   curp   = (const int*)d_in[2];
    const int*   subp   = (const int*)d_in[3];
    float* out = (float*)d_out;

    // ws: float4 P[2N] (256 KB) | uint dmin[2N] (64 KB)
    float4*   P    = (float4*)d_ws;
    unsigned* dmin = (unsigned*)(P + 2 * N);

    chamfer_prep_kernel<<<2 * N / BLK, BLK, 0, stream>>>(target, output, P, dmin);
    chamfer_dist_kernel<<<GRID, BLK, 0, stream>>>(P, dmin);
    chamfer_reduce_kernel<<<1, RBLK, 0, stream>>>(dmin, curp, subp, out);
}